// Round 1
// baseline (170.154 us; speedup 1.0000x reference)
//
#include <hip/hip_runtime.h>

#define BTOT   524288
#define TILES  4096            // BTOT / 128
#define TN     8               // Taylor order for expm

typedef __attribute__((ext_vector_type(8))) short s8v;   // 8 x bf16 bits
typedef __attribute__((ext_vector_type(4))) float f4v;

#define MFMA(a,b,c) __builtin_amdgcn_mfma_f32_16x16x32_bf16((a),(b),(c),0,0,0)

__device__ __forceinline__ short f2b(float f) {          // f32 -> bf16 (RNE)
  union { float f; unsigned u; } v; v.f = f;
  unsigned r = v.u + 0x7fffu + ((v.u >> 16) & 1u);
  return (short)(r >> 16);
}
__device__ __forceinline__ float b2f(short s) {
  union { float f; unsigned u; } v; v.u = ((unsigned)(unsigned short)s) << 16;
  return v.f;
}

// MFMA fragment load: lane holds M[row0 + (l&15)][kbase + (l>>4)*8 + i], i=0..7
__device__ __forceinline__ s8v ldfrag(const short* base, int row0, int kbase, int stride) {
  const int l = threadIdx.x & 63;
  return *(const s8v*)(base + (row0 + (l & 15)) * stride + kbase + (l >> 4) * 8);
}

// ---------------------------------------------------------------------------
// Kernel 1: K = expm(A*t/24); emit M1 = K[:, :64] (bf16) and W2K = K @ phi_W2
// (bf16). Single block, 512 threads. Split-bf16 (hi+lo) MFMA matmuls, R kept
// transposed in LDS as bf16 hi/lo so B-fragments are contiguous b128 reads.
// ---------------------------------------------------------------------------
__global__ __launch_bounds__(512, 2) void koop_prep(
    const float* __restrict__ tptr, const float* __restrict__ Ag,
    const float* __restrict__ W2g, short* __restrict__ m1out,
    short* __restrict__ w2kout) {
  extern __shared__ __align__(16) char smem[];
  short* RThi = (short*)smem;              // [128][136]  (RT[col][row] of R)
  short* RTlo = RThi + 128 * 136;          // [128][136]
  float* sW2  = (float*)(RTlo + 128 * 136);// [128][96] f32
  float* sred = sW2 + 128 * 96;            // [130]
  float* scratch = (float*)smem;           // [128][128] f32 alias (dead before RT writes)

  const int tid = threadIdx.x;
  const int lane = tid & 63, wid = tid >> 6;
  const int c_ = lane & 15, g_ = lane >> 4;
  const int mr = wid * 16;

  const float s = tptr[0] * (1.0f / 24.0f);
  for (int i = tid; i < 128 * 128; i += 512) scratch[i] = Ag[i] * s;
  for (int i = tid; i < 128 * 96;  i += 512) sW2[i] = W2g[i];
  __syncthreads();

  if (tid < 128) {                 // inf-norm row sums
    float su = 0.f;
    for (int j = 0; j < 128; ++j) su += fabsf(scratch[tid * 128 + j]);
    sred[tid] = su;
  }
  __syncthreads();
  if (tid == 0) {
    float m = 0.f;
    for (int i = 0; i < 128; ++i) m = fmaxf(m, sred[i]);
    int j = 0; float sc = 1.f;
    while (m > 0.5f && j < 20) { m *= 0.5f; sc *= 0.5f; ++j; }
    sred[128] = (float)j; sred[129] = sc;
  }
  __syncthreads();
  const int jsq = (int)sred[128];
  const float sc = sred[129];

  // A-fragments of Ys = A*s*2^-j (rows mr..mr+15), hi/lo, kept in regs
  s8v Ahi[4], Alo[4];
#pragma unroll
  for (int ks = 0; ks < 4; ++ks) {
    const float* p = scratch + (mr + c_) * 128 + ks * 32 + g_ * 8;
    f4v u = *(const f4v*)p, v = *(const f4v*)(p + 4);
    float vals[8] = {u[0], u[1], u[2], u[3], v[0], v[1], v[2], v[3]};
#pragma unroll
    for (int i = 0; i < 8; ++i) {
      float y = vals[i] * sc;
      short h = f2b(y);
      Ahi[ks][i] = h;
      Alo[ks][i] = f2b(y - b2f(h));
    }
  }
  float yv[32];                       // private copy for RT init
#pragma unroll
  for (int e = 0; e < 32; ++e) yv[e] = scratch[tid * 32 + e];
  __syncthreads();                    // scratch now dead

  // R_N = I + Ys/N, stored transposed hi/lo
#pragma unroll
  for (int e = 0; e < 32; ++e) {
    int idx = tid * 32 + e;
    int r = idx >> 7, c = idx & 127;
    float v = yv[e] * sc * (1.0f / TN) + ((r == c) ? 1.0f : 0.0f);
    short h = f2b(v);
    RThi[c * 136 + r] = h;
    RTlo[c * 136 + r] = f2b(v - b2f(h));
  }
  __syncthreads();

  // Horner: R <- I + (Ys/k) @ R,  k = N-1 .. 1
  for (int k = TN - 1; k >= 1; --k) {
    f4v acc[8];
#pragma unroll
    for (int nt = 0; nt < 8; ++nt) acc[nt] = (f4v){0.f, 0.f, 0.f, 0.f};
#pragma unroll
    for (int ks = 0; ks < 4; ++ks) {
#pragma unroll
      for (int nt = 0; nt < 8; ++nt) {
        s8v bh = ldfrag(RThi, nt * 16, ks * 32, 136);
        s8v bl = ldfrag(RTlo, nt * 16, ks * 32, 136);
        acc[nt] = MFMA(Ahi[ks], bh, acc[nt]);
        acc[nt] = MFMA(Alo[ks], bh, acc[nt]);
        acc[nt] = MFMA(Ahi[ks], bl, acc[nt]);
      }
    }
    __syncthreads();
    const float invk = 1.0f / (float)k;
#pragma unroll
    for (int nt = 0; nt < 8; ++nt)
#pragma unroll
      for (int r = 0; r < 4; ++r) {
        int row = mr + g_ * 4 + r, col = nt * 16 + c_;
        float v = acc[nt][r] * invk + ((row == col) ? 1.0f : 0.0f);
        short h = f2b(v);
        RThi[col * 136 + row] = h;
        RTlo[col * 136 + row] = f2b(v - b2f(h));
      }
    __syncthreads();
  }

  // squarings: R <- R @ R, jsq times
  for (int it = 0; it < jsq; ++it) {
    s8v Shi[4], Slo[4];
#pragma unroll
    for (int ks = 0; ks < 4; ++ks) {
      int m = mr + c_;
      int k0 = ks * 32 + g_ * 8;
#pragma unroll
      for (int i = 0; i < 8; ++i) {
        Shi[ks][i] = RThi[(k0 + i) * 136 + m];
        Slo[ks][i] = RTlo[(k0 + i) * 136 + m];
      }
    }
    f4v acc[8];
#pragma unroll
    for (int nt = 0; nt < 8; ++nt) acc[nt] = (f4v){0.f, 0.f, 0.f, 0.f};
#pragma unroll
    for (int ks = 0; ks < 4; ++ks) {
#pragma unroll
      for (int nt = 0; nt < 8; ++nt) {
        s8v bh = ldfrag(RThi, nt * 16, ks * 32, 136);
        s8v bl = ldfrag(RTlo, nt * 16, ks * 32, 136);
        acc[nt] = MFMA(Shi[ks], bh, acc[nt]);
        acc[nt] = MFMA(Slo[ks], bh, acc[nt]);
        acc[nt] = MFMA(Shi[ks], bl, acc[nt]);
      }
    }
    __syncthreads();
#pragma unroll
    for (int nt = 0; nt < 8; ++nt)
#pragma unroll
      for (int r = 0; r < 4; ++r) {
        int row = mr + g_ * 4 + r, col = nt * 16 + c_;
        float v = acc[nt][r];
        short h = f2b(v);
        RThi[col * 136 + row] = h;
        RTlo[col * 136 + row] = f2b(v - b2f(h));
      }
    __syncthreads();
  }

  // M1 = K[:, :64] as bf16 [128][64]
  for (int i = tid; i < 128 * 64; i += 512) {
    int n = i >> 6, kk = i & 63;
    m1out[i] = f2b(b2f(RThi[kk * 136 + n]) + b2f(RTlo[kk * 136 + n]));
  }

  // W2K = K @ phi_W2  -> bf16 [128][96]
  {
    s8v Shi[4], Slo[4];
#pragma unroll
    for (int ks = 0; ks < 4; ++ks) {
      int m = mr + c_;
      int k0 = ks * 32 + g_ * 8;
#pragma unroll
      for (int i = 0; i < 8; ++i) {
        Shi[ks][i] = RThi[(k0 + i) * 136 + m];
        Slo[ks][i] = RTlo[(k0 + i) * 136 + m];
      }
    }
    f4v acc[6];
#pragma unroll
    for (int nt = 0; nt < 6; ++nt) acc[nt] = (f4v){0.f, 0.f, 0.f, 0.f};
#pragma unroll
    for (int ks = 0; ks < 4; ++ks) {
#pragma unroll
      for (int nt = 0; nt < 6; ++nt) {
        s8v bh, bl;
#pragma unroll
        for (int i = 0; i < 8; ++i) {
          float v = sW2[(ks * 32 + g_ * 8 + i) * 96 + nt * 16 + c_];
          short h = f2b(v);
          bh[i] = h;
          bl[i] = f2b(v - b2f(h));
        }
        acc[nt] = MFMA(Shi[ks], bh, acc[nt]);
        acc[nt] = MFMA(Slo[ks], bh, acc[nt]);
        acc[nt] = MFMA(Shi[ks], bl, acc[nt]);
      }
    }
#pragma unroll
    for (int nt = 0; nt < 6; ++nt)
#pragma unroll
      for (int r = 0; r < 4; ++r)
        w2kout[(mr + g_ * 4 + r) * 96 + nt * 16 + c_] = f2b(acc[nt][r]);
  }
}

// ---------------------------------------------------------------------------
// Kernel 2: fused batched pipeline. 512 threads (8 waves), tile = 128 rows,
// all weights bf16 in LDS, +8-element row padding everywhere (stride mod 32
// banks = 4 -> <=2-way conflicts). Z overlays X+H; H2 overlays H tail.
// ---------------------------------------------------------------------------
__global__ __launch_bounds__(512, 2) void koop_main(
    const float* __restrict__ xg, const float* __restrict__ w1g,
    const float* __restrict__ b1g, const float* __restrict__ i1g,
    const float* __restrict__ bi1g, const float* __restrict__ i2g,
    const float* __restrict__ bi2g, const short* __restrict__ m1g,
    const short* __restrict__ w2kg, float* __restrict__ outg) {
  extern __shared__ __align__(16) char smem[];
  short* sW1  = (short*)smem;          // 96 x 72
  short* sM1  = sW1 + 96 * 72;         // 128 x 72
  short* sW2K = sM1 + 128 * 72;        // 128 x 104
  short* sI1  = sW2K + 128 * 104;      // 96 x 136
  short* sI2  = sI1 + 96 * 136;        // 64 x 104
  float* sB1  = (float*)(sI2 + 64 * 104);  // 96
  float* sBI1 = sB1 + 96;                  // 96
  float* sBI2 = sBI1 + 96;                 // 64
  short* U    = (short*)(sBI2 + 64);
  short* sX   = U;                     // 128 x 72
  short* sH   = U + 9216;              // 128 x 104
  short* sZ   = U;                     // 128 x 136 (overlays X+H after b3)
  short* sH2  = U + 17408;             // 128 x 104 (overlays H tail, dead then)

  const int tid = threadIdx.x;
  const int lane = tid & 63, wid = tid >> 6;
  const int c_ = lane & 15, g_ = lane >> 4;
  const int mr = wid * 16;

  // ---- stage weights into LDS (once per block) ----
  for (int i = tid; i < 96 * 64;  i += 512) sW1[(i >> 6) * 72 + (i & 63)] = f2b(w1g[i]);
  for (int i = tid; i < 128 * 64; i += 512) sM1[(i >> 6) * 72 + (i & 63)] = m1g[i];
  for (int i = tid; i < 128 * 96; i += 512) sW2K[(i / 96) * 104 + (i % 96)] = w2kg[i];
  for (int i = tid; i < 96 * 128; i += 512) sI1[(i >> 7) * 136 + (i & 127)] = f2b(i1g[i]);
  for (int i = tid; i < 64 * 96;  i += 512) sI2[(i / 96) * 104 + (i % 96)] = f2b(i2g[i]);
  if (tid < 96) sB1[tid] = b1g[tid];
  else if (tid < 192) sBI1[tid - 96] = bi1g[tid - 96];
  else if (tid < 256) sBI2[tid - 192] = bi2g[tid - 192];
  __syncthreads();

  const int xr = tid >> 2, xq = tid & 3;

  for (int tile = blockIdx.x; tile < TILES; tile += gridDim.x) {
    const size_t rowbase = (size_t)tile * 128;

    // (A) stage X tile -> bf16 LDS
    {
      const float* src = xg + (rowbase + xr) * 64 + xq * 16;
      f4v v0 = *(const f4v*)src, v1 = *(const f4v*)(src + 4);
      f4v v2 = *(const f4v*)(src + 8), v3 = *(const f4v*)(src + 12);
      s8v p0, p1;
      p0[0] = f2b(v0[0]); p0[1] = f2b(v0[1]); p0[2] = f2b(v0[2]); p0[3] = f2b(v0[3]);
      p0[4] = f2b(v1[0]); p0[5] = f2b(v1[1]); p0[6] = f2b(v1[2]); p0[7] = f2b(v1[3]);
      p1[0] = f2b(v2[0]); p1[1] = f2b(v2[1]); p1[2] = f2b(v2[2]); p1[3] = f2b(v2[3]);
      p1[4] = f2b(v3[0]); p1[5] = f2b(v3[1]); p1[6] = f2b(v3[2]); p1[7] = f2b(v3[3]);
      *(s8v*)(sX + xr * 72 + xq * 16) = p0;
      *(s8v*)(sX + xr * 72 + xq * 16 + 8) = p1;
    }
    __syncthreads();  // b1

    // stage 1: H = relu(X @ W1^T + b1)   [128 x 96]
    {
      s8v a0 = ldfrag(sX, mr, 0, 72), a1 = ldfrag(sX, mr, 32, 72);
      f4v acc[6];
#pragma unroll
      for (int nt = 0; nt < 6; ++nt) { float b = sB1[nt * 16 + c_]; acc[nt] = (f4v){b, b, b, b}; }
#pragma unroll
      for (int nt = 0; nt < 6; ++nt) acc[nt] = MFMA(a0, ldfrag(sW1, nt * 16, 0, 72), acc[nt]);
#pragma unroll
      for (int nt = 0; nt < 6; ++nt) acc[nt] = MFMA(a1, ldfrag(sW1, nt * 16, 32, 72), acc[nt]);
#pragma unroll
      for (int nt = 0; nt < 6; ++nt)
#pragma unroll
        for (int r = 0; r < 4; ++r) {
          float v = acc[nt][r]; v = v > 0.f ? v : 0.f;
          sH[(mr + g_ * 4 + r) * 104 + nt * 16 + c_] = f2b(v);
        }
    }
    __syncthreads();  // b2

    // stage 2: Z = X @ M1^T + H @ W2K^T   [128 x 128]
    f4v accz[8];
    {
      s8v ax0 = ldfrag(sX, mr, 0, 72), ax1 = ldfrag(sX, mr, 32, 72);
      s8v ah0 = ldfrag(sH, mr, 0, 104), ah1 = ldfrag(sH, mr, 32, 104), ah2 = ldfrag(sH, mr, 64, 104);
#pragma unroll
      for (int nt = 0; nt < 8; ++nt) accz[nt] = (f4v){0.f, 0.f, 0.f, 0.f};
#pragma unroll
      for (int nt = 0; nt < 8; ++nt) accz[nt] = MFMA(ax0, ldfrag(sM1, nt * 16, 0, 72), accz[nt]);
#pragma unroll
      for (int nt = 0; nt < 8; ++nt) accz[nt] = MFMA(ax1, ldfrag(sM1, nt * 16, 32, 72), accz[nt]);
#pragma unroll
      for (int nt = 0; nt < 8; ++nt) accz[nt] = MFMA(ah0, ldfrag(sW2K, nt * 16, 0, 104), accz[nt]);
#pragma unroll
      for (int nt = 0; nt < 8; ++nt) accz[nt] = MFMA(ah1, ldfrag(sW2K, nt * 16, 32, 104), accz[nt]);
#pragma unroll
      for (int nt = 0; nt < 8; ++nt) accz[nt] = MFMA(ah2, ldfrag(sW2K, nt * 16, 64, 104), accz[nt]);
    }
    __syncthreads();  // b3 (all reads of sX/sH done before Z overlays them)
#pragma unroll
    for (int nt = 0; nt < 8; ++nt)
#pragma unroll
      for (int r = 0; r < 4; ++r)
        sZ[(mr + g_ * 4 + r) * 136 + nt * 16 + c_] = f2b(accz[nt][r]);
    __syncthreads();  // b4

    // stage 3: H2 = relu(Z @ I1^T + bi1)   [128 x 96]
    {
      s8v a0 = ldfrag(sZ, mr, 0, 136), a1 = ldfrag(sZ, mr, 32, 136);
      s8v a2 = ldfrag(sZ, mr, 64, 136), a3 = ldfrag(sZ, mr, 96, 136);
      f4v acc[6];
#pragma unroll
      for (int nt = 0; nt < 6; ++nt) { float b = sBI1[nt * 16 + c_]; acc[nt] = (f4v){b, b, b, b}; }
#pragma unroll
      for (int nt = 0; nt < 6; ++nt) acc[nt] = MFMA(a0, ldfrag(sI1, nt * 16, 0, 136), acc[nt]);
#pragma unroll
      for (int nt = 0; nt < 6; ++nt) acc[nt] = MFMA(a1, ldfrag(sI1, nt * 16, 32, 136), acc[nt]);
#pragma unroll
      for (int nt = 0; nt < 6; ++nt) acc[nt] = MFMA(a2, ldfrag(sI1, nt * 16, 64, 136), acc[nt]);
#pragma unroll
      for (int nt = 0; nt < 6; ++nt) acc[nt] = MFMA(a3, ldfrag(sI1, nt * 16, 96, 136), acc[nt]);
#pragma unroll
      for (int nt = 0; nt < 6; ++nt)
#pragma unroll
        for (int r = 0; r < 4; ++r) {
          float v = acc[nt][r]; v = v > 0.f ? v : 0.f;
          sH2[(mr + g_ * 4 + r) * 104 + nt * 16 + c_] = f2b(v);
        }
    }
    __syncthreads();  // b5

    // stage 4: OUT = H2 @ I2^T + bi2   [128 x 64] -> global
    {
      s8v a0 = ldfrag(sH2, mr, 0, 104), a1 = ldfrag(sH2, mr, 32, 104), a2 = ldfrag(sH2, mr, 64, 104);
      f4v acc[4];
#pragma unroll
      for (int nt = 0; nt < 4; ++nt) { float b = sBI2[nt * 16 + c_]; acc[nt] = (f4v){b, b, b, b}; }
#pragma unroll
      for (int nt = 0; nt < 4; ++nt) acc[nt] = MFMA(a0, ldfrag(sI2, nt * 16, 0, 104), acc[nt]);
#pragma unroll
      for (int nt = 0; nt < 4; ++nt) acc[nt] = MFMA(a1, ldfrag(sI2, nt * 16, 32, 104), acc[nt]);
#pragma unroll
      for (int nt = 0; nt < 4; ++nt) acc[nt] = MFMA(a2, ldfrag(sI2, nt * 16, 64, 104), acc[nt]);
#pragma unroll
      for (int nt = 0; nt < 4; ++nt)
#pragma unroll
        for (int r = 0; r < 4; ++r)
          outg[(rowbase + mr + g_ * 4 + r) * 64 + nt * 16 + c_] = acc[nt][r];
    }
    // next (A) only touches sX (disjoint from sH2/weights) -> no extra barrier
  }
}

#define PREP_LDS (128 * 136 * 2 * 2 + 128 * 96 * 4 + 130 * 4)   // 119304 B
#define MAIN_LDS (98304 + 1024 + 61440)                          // 160768 B

extern "C" void kernel_launch(void* const* d_in, const int* in_sizes, int n_in,
                              void* d_out, int out_size, void* d_ws, size_t ws_size,
                              hipStream_t stream) {
  (void)in_sizes; (void)n_in; (void)out_size; (void)ws_size;
  const float* t     = (const float*)d_in[0];
  const float* x     = (const float*)d_in[1];
  const float* A     = (const float*)d_in[2];
  const float* phiW1 = (const float*)d_in[3];
  const float* phib1 = (const float*)d_in[4];
  const float* phiW2 = (const float*)d_in[5];
  const float* invW1 = (const float*)d_in[6];
  const float* invb1 = (const float*)d_in[7];
  const float* invW2 = (const float*)d_in[8];
  const float* invb2 = (const float*)d_in[9];
  float* out = (float*)d_out;

  short* m1w = (short*)d_ws;            // [128][64]  bf16
  short* w2k = m1w + 128 * 64;          // [128][96]  bf16

  (void)hipFuncSetAttribute((const void*)koop_prep,
                            hipFuncAttributeMaxDynamicSharedMemorySize, PREP_LDS);
  (void)hipFuncSetAttribute((const void*)koop_main,
                            hipFuncAttributeMaxDynamicSharedMemorySize, MAIN_LDS);

  koop_prep<<<1, 512, PREP_LDS, stream>>>(t, A, phiW2, m1w, w2k);
  koop_main<<<256, 512, MAIN_LDS, stream>>>(x, phiW1, phib1, invW1, invb1,
                                            invW2, invb2, m1w, w2k, out);
}